// Round 13
// baseline (155.020 us; speedup 1.0000x reference)
//
#include <hip/hip_runtime.h>
#include <hip/hip_bf16.h>

#define B_ 16
#define T_ 1500
#define E_ 512
#define A_ 512
#define H_ 4
#define C_ 10
#define K_ 201
#define M_ (B_*T_)   // 24000
#define KW_ 544      // 512 enc + 32 conv-channel K-rows

typedef __attribute__((ext_vector_type(8))) short short8v;    // 8 bf16
typedef __attribute__((ext_vector_type(4))) float f32x4;
typedef __attribute__((ext_vector_type(4))) unsigned short ushort4v;
typedef __attribute__((ext_vector_type(8))) unsigned short ushort8v;

typedef __attribute__((address_space(1))) const char gch;
typedef __attribute__((address_space(3))) char lch;

__device__ __forceinline__ void gload16(const void* g, void* l) {
    __builtin_amdgcn_global_load_lds((gch*)g, (lch*)l, 16, 0, 0);
}

__device__ inline unsigned short f2bf(float x) {
    unsigned int u = __float_as_uint(x);
    return (unsigned short)((u + 0x7fffu + ((u >> 16) & 1u)) >> 16);   // RNE
}

// ---- fused prep: enc->bf16 | W_enc transpose + W_conv pack | decA | conv ----
__global__ void k_prep(const float* __restrict__ enc, unsigned short* __restrict__ encB,
                       const float* __restrict__ Wenc, const float* __restrict__ Wconv,
                       unsigned short* __restrict__ WencTp,
                       const float* __restrict__ dec, const float* __restrict__ Wdec,
                       const float* __restrict__ benc, float* __restrict__ decA,
                       float* __restrict__ out,
                       const float* __restrict__ aw_step, const float* __restrict__ conv_w,
                       unsigned short* __restrict__ convA, float* __restrict__ wszero) {
    __shared__ float smemf[4456];
    int bid = blockIdx.x;
    int tid = threadIdx.x;

    if (bid < 6000) {                       // ---- enc [24000][512] f32 -> bf16
        int i = bid * 256 + tid;
        const float4* src = (const float4*)enc + (size_t)i * 2;
        float4 f0 = src[0], f1 = src[1];
        ushort8v o = { f2bf(f0.x), f2bf(f0.y), f2bf(f0.z), f2bf(f0.w),
                       f2bf(f1.x), f2bf(f1.y), f2bf(f1.z), f2bf(f1.w) };
        *(ushort8v*)&encB[(size_t)i * 8] = o;
        return;
    }
    if (bid < 7088) {                       // ---- W_enc transpose / W_conv pack
        int idx = bid - 6000;
        int bx = idx & 15, by = (idx >> 4) % 17, h = idx / 272;
        int tx = tid & 31, ty = tid >> 5;   // 32 x 8
        if (by == 16) {                     // conv-weight pack stripe
            int base = (h * 16 + bx) * 1024;
            #pragma unroll
            for (int k = 0; k < 4; k++) {
                int i2 = base + k * 256 + tid;
                int c = i2 & 31, n = (i2 >> 5) & 511, hh = i2 >> 14;
                float val = (c < C_) ? Wconv[(hh * C_ + c) * A_ + n] : 0.0f;
                WencTp[((size_t)(hh * A_ + n)) * KW_ + 512 + c] = f2bf(val);
            }
            return;
        }
        float (*tile)[33] = (float(*)[33])smemf;
        int e0 = bx * 32, a0 = by * 32;
        const float* src = Wenc + h * E_ * A_;
        #pragma unroll
        for (int i = 0; i < 4; i++) tile[ty + i*8][tx] = src[(e0 + ty + i*8) * A_ + a0 + tx];
        __syncthreads();
        unsigned short* dst = WencTp + (size_t)h * A_ * KW_;
        #pragma unroll
        for (int i = 0; i < 4; i++) dst[(size_t)(a0 + ty + i*8) * KW_ + e0 + tx] = f2bf(tile[tx][ty + i*8]);
        return;
    }
    if (bid < 7152) {                       // ---- decA + zero context_vec out
        int bh = bid - 7088, b = bh >> 2, h = bh & 3;
        int a = tid;
        if (bh < 32) out[bh * 256 + a] = 0.0f;
        float acc0 = 0.f, acc1 = 0.f;
        const float* W = Wdec + h * E_ * A_;
        const float* x = dec + b * 512;
        for (int d = 0; d < 512; d++) {
            float s = x[d];
            acc0 += s * W[d * A_ + a];
            acc1 += s * W[d * A_ + a + 256];
        }
        decA[bh * A_ + a]       = acc0 + benc[h * A_ + a];
        decA[bh * A_ + a + 256] = acc1 + benc[h * A_ + a + 256];
        return;
    }
    {                                       // ---- grouped conv + zero energy/ctx
        int i = bid - 7152;
        int b = i & 15, h = (i >> 4) & 3, tc = i >> 6;
        int t0 = tc * 250;
        float* seg = smemf;
        unsigned short* outl = (unsigned short*)(smemf + 456);
        {   // zero energy (96000 f32) + ctx (32768 f32)
            int idx = (i * 256 + tid) * 2;
            if (idx < 128768)     wszero[idx] = 0.0f;
            if (idx + 1 < 128768) wszero[idx + 1] = 0.0f;
        }
        for (int idx = tid; idx < 450; idx += 256) {
            int tt = t0 - 100 + idx;
            seg[idx] = (tt >= 0 && tt < T_) ? aw_step[(b * T_ + tt) * H_ + h] : 0.0f;
        }
        for (int idx = tid; idx < 8000; idx += 256) outl[idx] = 0;
        __syncthreads();
        if (tid < 250) {
            float acc[10] = {0,0,0,0,0,0,0,0,0,0};
            const float* cw = conv_w + h * C_ * K_;
            for (int k = 0; k < K_; k++) {
                float sv = seg[tid + k];
                #pragma unroll
                for (int c = 0; c < 10; c++) acc[c] += sv * cw[c * K_ + k];
            }
            #pragma unroll
            for (int c = 0; c < 10; c++) outl[tid * 32 + c] = f2bf(acc[c]);
        }
        __syncthreads();
        unsigned short* dst = convA + ((size_t)h * M_ + (size_t)b * T_ + t0) * 32;
        for (int idx = tid; idx < 2000; idx += 256)
            *(ushort4v*)&dst[idx * 4] = *(const ushort4v*)&outl[idx * 4];
    }
}

// ---- fused energy GEMM: 128x128, BK=32, 17 K-steps, TRIPLE-buffered with
// SINGLE barrier per step: stage is issued AFTER the barrier, so the buffer
// staged (bn2 = computed at s-1) is safe -- all waves' reads of it completed
// before they reached this barrier. vmcnt ledger: outstanding = batch_s +
// batch_{s+1} (4+4); vmcnt(4) drains batch_s; vmcnt(0) at s=16.
// Swizzle both-sides (rule #21) as R10/R12 (verified conflict-free).
// MFMA operands swapped (C^T): epilogue reduce = 2 shfl (R12, verified).
__launch_bounds__(256, 3)
__global__ void k_energy(const unsigned short* __restrict__ encB,
                         const unsigned short* __restrict__ WencTp,
                         const unsigned short* __restrict__ convA,
                         const float* __restrict__ decA,
                         const float* __restrict__ v,
                         float* __restrict__ energy) {
    __shared__ unsigned short As[3][4096];   // [buf][128 rows x 32 k]
    __shared__ unsigned short Bs[3][4096];
    int m0 = blockIdx.x * 128;                // 188 M-tiles (last clamps rows)
    int h  = blockIdx.y >> 2;
    int n0 = (blockIdx.y & 3) * 128;
    int tid = threadIdx.x;
    int lane = tid & 63, w = tid >> 6;
    int wr = w >> 1, wc = w & 1;
    int lc = lane & 15, lr16 = lane >> 4;

    // staging: 8 chunks x 16 rows; row = chunk*16 + (lane>>2), 16B slot lane&3;
    // pre-swizzled source slot = slot ^ ((row>>1)&3)  [verified: conflicts = 0]
    int srow  = lane >> 2;
    int sslot = (lane & 3) ^ ((lane >> 3) & 3);

    const char* pa[2]; const char* pb[2]; const char* pca[2];
    #pragma unroll
    for (int i = 0; i < 2; i++) {
        int c = i * 4 + w;                  // chunk 0..7
        int row = c * 16 + srow;
        int grow = min(m0 + row, M_ - 1);
        pa[i]  = (const char*)encB + ((size_t)grow * 512 + sslot * 8) * 2;
        pb[i]  = (const char*)WencTp + ((size_t)(h * 512 + n0 + row) * KW_ + sslot * 8) * 2;
        pca[i] = (const char*)convA + (((size_t)h * M_ + grow) * 32 + sslot * 8) * 2;
    }

    // ds_read swizzled k-slot (elems); row parity comes from lc
    int kslot = (lr16 ^ ((lc >> 1) & 3)) * 8;

    f32x4 acc[4][4] = {};

    // prologue: stage batch0 -> buf0, batch1 -> buf1 (8 loads in flight)
    #pragma unroll
    for (int i = 0; i < 2; i++) {
        int c = i * 4 + w;
        gload16(pa[i],      (char*)As[0] + c * 1024);
        gload16(pb[i],      (char*)Bs[0] + c * 1024);
        gload16(pa[i] + 64, (char*)As[1] + c * 1024);
        gload16(pb[i] + 64, (char*)Bs[1] + c * 1024);
    }

    int bc = 0, bn2 = 2;                     // compute buf; stage target (bc+2 mod 3)
    for (int s = 0; s < 17; ++s) {
        if (s < 16) asm volatile("s_waitcnt vmcnt(4)" ::: "memory");
        else        asm volatile("s_waitcnt vmcnt(0)" ::: "memory");
        __builtin_amdgcn_s_barrier();         // batch_s landed block-wide;
        __builtin_amdgcn_sched_barrier(0);    // also: all reads of bn2 are done
        int t = s + 2;
        if (t <= 16) {                        // stage batch_{s+2} into bn2
            #pragma unroll
            for (int i = 0; i < 2; i++) {
                int c = i * 4 + w;
                const char* asrc = (t < 16) ? pa[i] + t * 64 : pca[i];
                const char* bsrc = (t < 16) ? pb[i] + t * 64 : pb[i] + 16 * 64;
                gload16(asrc, (char*)As[bn2] + c * 1024);
                gload16(bsrc, (char*)Bs[bn2] + c * 1024);
            }
        }
        {
            short8v a[4], b[4];
            #pragma unroll
            for (int mi = 0; mi < 4; mi++)
                a[mi] = *(const short8v*)&As[bc][(wr * 64 + mi * 16 + lc) * 32 + kslot];
            #pragma unroll
            for (int ni = 0; ni < 4; ni++)
                b[ni] = *(const short8v*)&Bs[bc][(wc * 64 + ni * 16 + lc) * 32 + kslot];
            // swapped operands -> acc holds C^T: lane col = m (lc), rows = n
            #pragma unroll
            for (int mi = 0; mi < 4; mi++)
                #pragma unroll
                for (int ni = 0; ni < 4; ni++)
                    acc[mi][ni] = __builtin_amdgcn_mfma_f32_16x16x32_bf16(b[ni], a[mi], acc[mi][ni], 0, 0, 0);
        }
        __builtin_amdgcn_sched_barrier(0);    // keep reads inside this step
        bc  = (bc  == 2) ? 0 : bc + 1;
        bn2 = (bn2 == 2) ? 0 : bn2 + 1;
    }

    // epilogue: C^T layout -> m = wr*64+mi*16+lc ; n = wc*64+ni*16+lr16*4+r.
    #pragma unroll
    for (int mi = 0; mi < 4; mi++) {
        int mrow = m0 + wr * 64 + mi * 16 + lc;
        if (mrow < M_) {
            int bb = mrow / 1500;
            const float* dA = decA + (bb * 4 + h) * 512;
            float s = 0.f;
            #pragma unroll
            for (int ni = 0; ni < 4; ni++) {
                #pragma unroll
                for (int r = 0; r < 4; r++) {
                    int n = n0 + wc * 64 + ni * 16 + lr16 * 4 + r;
                    float xv = acc[mi][ni][r] + dA[n];
                    // tanh(x) = 1 - 2/(e^2x + 1); saturates correctly at +-inf
                    float tt = __builtin_amdgcn_rcpf(__expf(2.0f * xv) + 1.0f);
                    float vv = v[h * 512 + n];
                    s += __builtin_fmaf(-2.0f * tt, vv, vv);
                }
            }
            s += __shfl_xor(s, 16);
            s += __shfl_xor(s, 32);
            if (lr16 == 0) atomicAdd(&energy[(size_t)mrow * 4 + h], s);
        }
    }
}

// ---- fused softmax + context: block (b,tc) redundantly computes per-h
// softmax stats from energy[b] (24KB, L2-hot), emits its own aw slice
// (global write = the aw output) and accumulates ctx via atomics.
__global__ void k_ctx(const unsigned short* __restrict__ encB,
                      const float* __restrict__ energy,
                      const int* __restrict__ xlens,
                      float* __restrict__ aw, float* __restrict__ ctx) {
    __shared__ float sE[6000];     // energy[b][t][h], masked
    __shared__ float s_aw[500];
    __shared__ float sMS[8];       // m[4], inv_sum[4]
    int b = blockIdx.x, tc = blockIdx.y;   // grid (16, 12)
    int t0 = tc * 125;
    int tid = threadIdx.x;
    int len = xlens[b];
    const float* eb = energy + (size_t)b * 6000;
    for (int idx = tid; idx < 6000; idx += 256) {
        int t = idx >> 2;
        sE[idx] = (t < len) ? eb[idx] : 0.0f;
    }
    __syncthreads();
    {   // wave wv reduces head h = wv over T
        int wv = tid >> 6, lane = tid & 63;
        float m = -1e30f;
        for (int i = lane; i < T_; i += 64) m = fmaxf(m, sE[i * 4 + wv]);
        #pragma unroll
        for (int mk = 1; mk < 64; mk <<= 1) m = fmaxf(m, __shfl_xor(m, mk));
        float ssum = 0.f;
        for (int i = lane; i < T_; i += 64) ssum += __expf(sE[i * 4 + wv] - m);
        #pragma unroll
        for (int mk = 1; mk < 64; mk <<= 1) ssum += __shfl_xor(ssum, mk);
        if (lane == 0) { sMS[wv] = m; sMS[4 + wv] = 1.0f / ssum; }
    }
    __syncthreads();
    // aw slice [t0, t0+125): compute, write global aw, keep in LDS for ctx
    for (int idx = tid; idx < 500; idx += 256) {
        int hh = idx & 3;
        float av = __expf(sE[t0 * 4 + idx] - sMS[hh]) * sMS[4 + hh];
        s_aw[idx] = av;
        aw[(size_t)b * 6000 + t0 * 4 + idx] = av;
    }
    __syncthreads();
    int e = tid * 2;
    float a00=0,a01=0,a10=0,a11=0,a20=0,a21=0,a30=0,a31=0;
    for (int tl = 0; tl < 125; tl++) {
        unsigned int u = *(const unsigned int*)&encB[(size_t)(b * T_ + t0 + tl) * E_ + e];
        float e0 = __uint_as_float((u & 0xffffu) << 16);
        float e1 = __uint_as_float(u & 0xffff0000u);
        float w0 = s_aw[tl*4+0], w1 = s_aw[tl*4+1], w2 = s_aw[tl*4+2], w3 = s_aw[tl*4+3];
        a00 += e0*w0; a01 += e1*w0; a10 += e0*w1; a11 += e1*w1;
        a20 += e0*w2; a21 += e1*w2; a30 += e0*w3; a31 += e1*w3;
    }
    atomicAdd(&ctx[b*2048 + 0*512 + e],   a00); atomicAdd(&ctx[b*2048 + 0*512 + e+1], a01);
    atomicAdd(&ctx[b*2048 + 1*512 + e],   a10); atomicAdd(&ctx[b*2048 + 1*512 + e+1], a11);
    atomicAdd(&ctx[b*2048 + 2*512 + e],   a20); atomicAdd(&ctx[b*2048 + 2*512 + e+1], a21);
    atomicAdd(&ctx[b*2048 + 3*512 + e],   a30); atomicAdd(&ctx[b*2048 + 3*512 + e+1], a31);
}

// ---- context_vec[b][j] = ctx[b][:] @ W_mha[:,j] + b_mha[j] ----
__global__ void k_proj(const float* __restrict__ ctx, const float* __restrict__ Wmha,
                       const float* __restrict__ bmha, float* __restrict__ out) {
    __shared__ float s_c[256];
    int b = blockIdx.x, ic = blockIdx.y;
    int tid = threadIdx.x;   // 512
    if (tid < 256) s_c[tid] = ctx[b * 2048 + ic * 256 + tid];
    __syncthreads();
    float acc = (ic == 0) ? bmha[tid] : 0.0f;
    const float* W = Wmha + (size_t)ic * 256 * 512;
    for (int i = 0; i < 256; i++) acc += s_c[i] * W[i * 512 + tid];
    atomicAdd(&out[b * 512 + tid], acc);
}

extern "C" void kernel_launch(void* const* d_in, const int* in_sizes, int n_in,
                              void* d_out, int out_size, void* d_ws, size_t ws_size,
                              hipStream_t stream) {
    const float* enc   = (const float*)d_in[0];
    const int*   xlens = (const int*)  d_in[1];
    const float* dec   = (const float*)d_in[2];
    const float* aw_st = (const float*)d_in[3];
    const float* Wenc  = (const float*)d_in[4];
    const float* benc  = (const float*)d_in[5];
    const float* Wdec  = (const float*)d_in[6];
    const float* Wconv = (const float*)d_in[7];
    const float* convw = (const float*)d_in[8];
    const float* v     = (const float*)d_in[9];
    const float* Wmha  = (const float*)d_in[10];
    const float* bmha  = (const float*)d_in[11];
    float* out = (float*)d_out;            // [8192 context_vec][96000 aw]

    char* ws = (char*)d_ws;
    float* energy          = (float*)(ws);                    // 384000 B
    float* ctx             = (float*)(ws + 384000);           // 131072 B
    float* decA            = (float*)(ws + 515072);           // 131072 B
    unsigned short* WencTp = (unsigned short*)(ws + 646144);  // 4*512*544*2 = 2228224 B
    unsigned short* convA  = (unsigned short*)(ws + 2874368); // 4*24000*32*2 = 6144000 B
    unsigned short* encB   = (unsigned short*)(ws + 9018368); // 24000*512*2 = 24576000 B
    float* aw = out + 8192;

    k_prep   <<<7536, 256, 0, stream>>>(enc, encB, Wenc, Wconv, WencTp,
                                        dec, Wdec, benc, decA, out,
                                        aw_st, convw, convA, (float*)ws);
    k_energy <<<dim3(188, 16), 256, 0, stream>>>(encB, WencTp, convA, decA, v, energy);
    k_ctx    <<<dim3(16, 12), 256, 0, stream>>>(encB, energy, xlens, aw, ctx);
    k_proj   <<<dim3(16, 8), 512, 0, stream>>>(ctx, Wmha, bmha, out);
}

// Round 14
// 153.024 us; speedup vs baseline: 1.0130x; 1.0130x over previous
//
#include <hip/hip_runtime.h>
#include <hip/hip_bf16.h>

#define B_ 16
#define T_ 1500
#define E_ 512
#define A_ 512
#define H_ 4
#define C_ 10
#define K_ 201
#define M_ (B_*T_)   // 24000
#define KW_ 576      // 512 enc + 2x32 conv K-rows (head-even [512,544), head-odd [544,576))

typedef __attribute__((ext_vector_type(8))) short short8v;    // 8 bf16
typedef __attribute__((ext_vector_type(4))) float f32x4;
typedef __attribute__((ext_vector_type(4))) unsigned short ushort4v;
typedef __attribute__((ext_vector_type(8))) unsigned short ushort8v;

typedef __attribute__((address_space(1))) const char gch;
typedef __attribute__((address_space(3))) char lch;

__device__ __forceinline__ void gload16(const void* g, void* l) {
    __builtin_amdgcn_global_load_lds((gch*)g, (lch*)l, 16, 0, 0);
}

__device__ inline unsigned short f2bf(float x) {
    unsigned int u = __float_as_uint(x);
    return (unsigned short)((u + 0x7fffu + ((u >> 16) & 1u)) >> 16);   // RNE
}

// ---- fused prep: enc->bf16 | W_enc transpose + W_conv pack | decA | conv ----
__global__ void k_prep(const float* __restrict__ enc, unsigned short* __restrict__ encB,
                       const float* __restrict__ Wenc, const float* __restrict__ Wconv,
                       unsigned short* __restrict__ WencTp,
                       const float* __restrict__ dec, const float* __restrict__ Wdec,
                       const float* __restrict__ benc, float* __restrict__ decA,
                       float* __restrict__ out,
                       const float* __restrict__ aw_step, const float* __restrict__ conv_w,
                       unsigned short* __restrict__ convAB, float* __restrict__ wszero) {
    __shared__ float smemf[4456];
    int bid = blockIdx.x;
    int tid = threadIdx.x;

    if (bid < 6000) {                       // ---- enc [24000][512] f32 -> bf16
        int i = bid * 256 + tid;
        const float4* src = (const float4*)enc + (size_t)i * 2;
        float4 f0 = src[0], f1 = src[1];
        ushort8v o = { f2bf(f0.x), f2bf(f0.y), f2bf(f0.z), f2bf(f0.w),
                       f2bf(f1.x), f2bf(f1.y), f2bf(f1.z), f2bf(f1.w) };
        *(ushort8v*)&encB[(size_t)i * 8] = o;
        return;
    }
    if (bid < 7088) {                       // ---- W_enc transpose / W_conv pack
        int idx = bid - 6000;
        int bx = idx & 15, by = (idx >> 4) % 17, h = idx / 272;
        int tx = tid & 31, ty = tid >> 5;   // 32 x 8
        if (by == 16) {                     // conv-weight pack: 4*512*64 = 131072 slots
            int base = (h * 16 + bx) * 2048;
            #pragma unroll
            for (int k = 0; k < 8; k++) {
                int i2 = base + k * 256 + tid;   // < 131072
                int c6 = i2 & 63, n = (i2 >> 6) & 511, hh = i2 >> 15;
                int own = ((c6 >> 5) == (hh & 1));
                int ch = c6 & 31;
                float val = (own && ch < C_) ? Wconv[(hh * C_ + ch) * A_ + n] : 0.0f;
                WencTp[((size_t)(hh * A_ + n)) * KW_ + 512 + c6] = f2bf(val);
            }
            return;
        }
        float (*tile)[33] = (float(*)[33])smemf;
        int e0 = bx * 32, a0 = by * 32;
        const float* src = Wenc + h * E_ * A_;
        #pragma unroll
        for (int i = 0; i < 4; i++) tile[ty + i*8][tx] = src[(e0 + ty + i*8) * A_ + a0 + tx];
        __syncthreads();
        unsigned short* dst = WencTp + (size_t)h * A_ * KW_;
        #pragma unroll
        for (int i = 0; i < 4; i++) dst[(size_t)(a0 + ty + i*8) * KW_ + e0 + tx] = f2bf(tile[tx][ty + i*8]);
        return;
    }
    if (bid < 7152) {                       // ---- decA + zero context_vec out
        int bh = bid - 7088, b = bh >> 2, h = bh & 3;
        int a = tid;
        if (bh < 32) out[bh * 256 + a] = 0.0f;
        float acc0 = 0.f, acc1 = 0.f;
        const float* W = Wdec + h * E_ * A_;
        const float* x = dec + b * 512;
        for (int d = 0; d < 512; d++) {
            float s = x[d];
            acc0 += s * W[d * A_ + a];
            acc1 += s * W[d * A_ + a + 256];
        }
        decA[bh * A_ + a]       = acc0 + benc[h * A_ + a];
        decA[bh * A_ + a + 256] = acc1 + benc[h * A_ + a + 256];
        return;
    }
    {                                       // ---- grouped conv + zero energy/ctx
        int i = bid - 7152;
        int b = i & 15, h = (i >> 4) & 3, tc = i >> 6;
        int t0 = tc * 250;
        float* seg = smemf;
        unsigned short* outl = (unsigned short*)(smemf + 456);
        {   // zero energy (96000 f32) + ctx (32768 f32)
            int idx = (i * 256 + tid) * 2;
            if (idx < 128768)     wszero[idx] = 0.0f;
            if (idx + 1 < 128768) wszero[idx + 1] = 0.0f;
        }
        for (int idx = tid; idx < 450; idx += 256) {
            int tt = t0 - 100 + idx;
            seg[idx] = (tt >= 0 && tt < T_) ? aw_step[(b * T_ + tt) * H_ + h] : 0.0f;
        }
        for (int idx = tid; idx < 8000; idx += 256) outl[idx] = 0;
        __syncthreads();
        if (tid < 250) {
            float acc[10] = {0,0,0,0,0,0,0,0,0,0};
            const float* cw = conv_w + h * C_ * K_;
            for (int k = 0; k < K_; k++) {
                float sv = seg[tid + k];
                #pragma unroll
                for (int c = 0; c < 10; c++) acc[c] += sv * cw[c * K_ + k];
            }
            #pragma unroll
            for (int c = 0; c < 10; c++) outl[tid * 32 + c] = f2bf(acc[c]);
        }
        __syncthreads();
        // convAB[hp][m][64]: head-even -> cols [0,32), head-odd -> [32,64)
        unsigned short* dst = convAB + ((size_t)(h >> 1) * M_ + (size_t)b * T_ + t0) * 64 + (h & 1) * 32;
        for (int idx = tid; idx < 2000; idx += 256) {
            int row = idx >> 3, q = idx & 7;
            *(ushort4v*)&dst[row * 64 + q * 4] = *(const ushort4v*)&outl[row * 32 + q * 4];
        }
    }
}

// ---- fused energy GEMM: 128x128 per HEAD-PAIR, BK=32, 18 uniform K-steps
// (16 enc + 2 conv via complementary zero-padding). A-tile staged once,
// used by BOTH heads' B-tiles: 12 ds_read -> 32 MFMA per step (2x density).
// TRIPLE-buffered, single barrier per step (R13-verified): stage AFTER the
// barrier into the buffer computed last step. vmcnt: batches of 6 ->
// vmcnt(6) steady, vmcnt(0) at final step. Swizzle both-sides (rule #21,
// verified conflict-free). Swapped MFMA operands (C^T) -> 2-shfl epilogue.
__launch_bounds__(256, 2)
__global__ void k_energy(const unsigned short* __restrict__ encB,
                         const unsigned short* __restrict__ WencTp,
                         const unsigned short* __restrict__ convAB,
                         const float* __restrict__ decA,
                         const float* __restrict__ v,
                         float* __restrict__ energy) {
    __shared__ unsigned short As [3][4096];   // [buf][128 rows x 32 k]
    __shared__ unsigned short BsA[3][4096];
    __shared__ unsigned short BsB[3][4096];
    int m0 = blockIdx.x * 128;                // 188 M-tiles (last clamps rows)
    int hp = blockIdx.y >> 2;                 // head pair 0..1
    int n0 = (blockIdx.y & 3) * 128;
    int h0 = hp * 2, h1 = h0 + 1;
    int tid = threadIdx.x;
    int lane = tid & 63, w = tid >> 6;
    int wr = w >> 1, wc = w & 1;
    int lc = lane & 15, lr16 = lane >> 4;

    int srow  = lane >> 2;
    int sslot = (lane & 3) ^ ((lane >> 3) & 3);

    const char* pa[2]; const char* pbA[2]; const char* pbB[2]; const char* pca[2];
    #pragma unroll
    for (int i = 0; i < 2; i++) {
        int c = i * 4 + w;                  // chunk 0..7
        int row = c * 16 + srow;
        int grow = min(m0 + row, M_ - 1);
        pa[i]  = (const char*)encB + ((size_t)grow * 512 + sslot * 8) * 2;
        pbA[i] = (const char*)WencTp + ((size_t)(h0 * 512 + n0 + row) * KW_ + sslot * 8) * 2;
        pbB[i] = (const char*)WencTp + ((size_t)(h1 * 512 + n0 + row) * KW_ + sslot * 8) * 2;
        pca[i] = (const char*)convAB + (((size_t)hp * M_ + grow) * 64 + sslot * 8) * 2;
    }

    int kslot = (lr16 ^ ((lc >> 1) & 3)) * 8;

    f32x4 accA[4][4] = {};
    f32x4 accB[4][4] = {};

    // prologue: batch0 -> buf0, batch1 -> buf1 (12 loads in flight)
    #pragma unroll
    for (int i = 0; i < 2; i++) {
        int c = i * 4 + w;
        gload16(pa[i],       (char*)As[0]  + c * 1024);
        gload16(pbA[i],      (char*)BsA[0] + c * 1024);
        gload16(pbB[i],      (char*)BsB[0] + c * 1024);
        gload16(pa[i] + 64,  (char*)As[1]  + c * 1024);
        gload16(pbA[i] + 64, (char*)BsA[1] + c * 1024);
        gload16(pbB[i] + 64, (char*)BsB[1] + c * 1024);
    }

    int bc = 0, bn2 = 2;
    for (int s = 0; s < 18; ++s) {
        if (s < 17) asm volatile("s_waitcnt vmcnt(6)" ::: "memory");
        else        asm volatile("s_waitcnt vmcnt(0)" ::: "memory");
        __builtin_amdgcn_s_barrier();         // batch_s landed; reads of bn2 done
        __builtin_amdgcn_sched_barrier(0);
        int t = s + 2;
        if (t <= 17) {                        // stage batch_{s+2} into bn2
            #pragma unroll
            for (int i = 0; i < 2; i++) {
                int c = i * 4 + w;
                const char* asrc = (t < 16) ? pa[i] + t * 64 : pca[i] + (t - 16) * 64;
                gload16(asrc,           (char*)As[bn2]  + c * 1024);
                gload16(pbA[i] + t * 64, (char*)BsA[bn2] + c * 1024);
                gload16(pbB[i] + t * 64, (char*)BsB[bn2] + c * 1024);
            }
        }
        {
            short8v a[4], bA[4], bB[4];
            #pragma unroll
            for (int mi = 0; mi < 4; mi++)
                a[mi] = *(const short8v*)&As[bc][(wr * 64 + mi * 16 + lc) * 32 + kslot];
            #pragma unroll
            for (int ni = 0; ni < 4; ni++) {
                bA[ni] = *(const short8v*)&BsA[bc][(wc * 64 + ni * 16 + lc) * 32 + kslot];
                bB[ni] = *(const short8v*)&BsB[bc][(wc * 64 + ni * 16 + lc) * 32 + kslot];
            }
            #pragma unroll
            for (int mi = 0; mi < 4; mi++)
                #pragma unroll
                for (int ni = 0; ni < 4; ni++) {
                    accA[mi][ni] = __builtin_amdgcn_mfma_f32_16x16x32_bf16(bA[ni], a[mi], accA[mi][ni], 0, 0, 0);
                    accB[mi][ni] = __builtin_amdgcn_mfma_f32_16x16x32_bf16(bB[ni], a[mi], accB[mi][ni], 0, 0, 0);
                }
        }
        __builtin_amdgcn_sched_barrier(0);
        bc  = (bc  == 2) ? 0 : bc + 1;
        bn2 = (bn2 == 2) ? 0 : bn2 + 1;
    }

    // epilogue: C^T layout -> m = wr*64+mi*16+lc ; n = wc*64+ni*16+lr16*4+r.
    #pragma unroll
    for (int hd = 0; hd < 2; hd++) {
        int h = h0 + hd;
        #pragma unroll
        for (int mi = 0; mi < 4; mi++) {
            int mrow = m0 + wr * 64 + mi * 16 + lc;
            if (mrow < M_) {
                int bb = mrow / 1500;
                const float* dA = decA + (bb * 4 + h) * 512;
                float s = 0.f;
                #pragma unroll
                for (int ni = 0; ni < 4; ni++) {
                    #pragma unroll
                    for (int r = 0; r < 4; r++) {
                        int n = n0 + wc * 64 + ni * 16 + lr16 * 4 + r;
                        float xv = (hd ? accB[mi][ni][r] : accA[mi][ni][r]) + dA[n];
                        // tanh(x) = 1 - 2/(e^2x + 1); saturates correctly at +-inf
                        float tt = __builtin_amdgcn_rcpf(__expf(2.0f * xv) + 1.0f);
                        float vv = v[h * 512 + n];
                        s += __builtin_fmaf(-2.0f * tt, vv, vv);
                    }
                }
                s += __shfl_xor(s, 16);
                s += __shfl_xor(s, 32);
                if (lr16 == 0) atomicAdd(&energy[(size_t)mrow * 4 + h], s);
            }
        }
    }
}

// ---- masked softmax over T ----
__global__ void k_softmax(const float* __restrict__ energy, const int* __restrict__ xlens,
                          float* __restrict__ aw) {
    __shared__ float red[8];
    int b = blockIdx.x, h = blockIdx.y;
    int tid = threadIdx.x;
    int len = xlens[b];
    float e[6];
    float m = -1e30f;
    #pragma unroll
    for (int i = 0; i < 6; i++) {
        int t = tid + i * 256;
        float val = 0.0f;
        if (t < T_) {
            val = (t < len) ? energy[(size_t)(b * T_ + t) * H_ + h] : 0.0f;
            m = fmaxf(m, val);
        }
        e[i] = val;
    }
    #pragma unroll
    for (int mk = 1; mk < 64; mk <<= 1) m = fmaxf(m, __shfl_xor(m, mk));
    if ((tid & 63) == 0) red[tid >> 6] = m;
    __syncthreads();
    m = fmaxf(fmaxf(red[0], red[1]), fmaxf(red[2], red[3]));
    float ssum = 0.f;
    #pragma unroll
    for (int i = 0; i < 6; i++) {
        int t = tid + i * 256;
        if (t < T_) { e[i] = expf(e[i] - m); ssum += e[i]; }
    }
    #pragma unroll
    for (int mk = 1; mk < 64; mk <<= 1) ssum += __shfl_xor(ssum, mk);
    if ((tid & 63) == 0) red[4 + (tid >> 6)] = ssum;
    __syncthreads();
    float inv = 1.0f / (red[4] + red[5] + red[6] + red[7]);
    #pragma unroll
    for (int i = 0; i < 6; i++) {
        int t = tid + i * 256;
        if (t < T_) aw[(size_t)(b * T_ + t) * H_ + h] = e[i] * inv;
    }
}

// ---- ctx[b][h][e] = sum_t aw[b,t,h] * encB[b,t,e]  (bf16 enc read) ----
__global__ void k_ctx(const unsigned short* __restrict__ encB, const float* __restrict__ aw,
                      float* __restrict__ ctx) {
    __shared__ float s_aw[500];
    int b = blockIdx.x, tc = blockIdx.y;   // grid (16, 12)
    int t0 = tc * 125;
    int tid = threadIdx.x;
    for (int idx = tid; idx < 500; idx += 256)
        s_aw[idx] = aw[(size_t)b * T_ * H_ + t0 * H_ + idx];
    __syncthreads();
    int e = tid * 2;
    float a00=0,a01=0,a10=0,a11=0,a20=0,a21=0,a30=0,a31=0;
    for (int tl = 0; tl < 125; tl++) {
        unsigned int u = *(const unsigned int*)&encB[(size_t)(b * T_ + t0 + tl) * E_ + e];
        float e0 = __uint_as_float((u & 0xffffu) << 16);
        float e1 = __uint_as_float(u & 0xffff0000u);
        float w0 = s_aw[tl*4+0], w1 = s_aw[tl*4+1], w2 = s_aw[tl*4+2], w3 = s_aw[tl*4+3];
        a00 += e0*w0; a01 += e1*w0; a10 += e0*w1; a11 += e1*w1;
        a20 += e0*w2; a21 += e1*w2; a30 += e0*w3; a31 += e1*w3;
    }
    atomicAdd(&ctx[b*2048 + 0*512 + e],   a00); atomicAdd(&ctx[b*2048 + 0*512 + e+1], a01);
    atomicAdd(&ctx[b*2048 + 1*512 + e],   a10); atomicAdd(&ctx[b*2048 + 1*512 + e+1], a11);
    atomicAdd(&ctx[b*2048 + 2*512 + e],   a20); atomicAdd(&ctx[b*2048 + 2*512 + e+1], a21);
    atomicAdd(&ctx[b*2048 + 3*512 + e],   a30); atomicAdd(&ctx[b*2048 + 3*512 + e+1], a31);
}

// ---- context_vec[b][j] = ctx[b][:] @ W_mha[:,j] + b_mha[j] ----
__global__ void k_proj(const float* __restrict__ ctx, const float* __restrict__ Wmha,
                       const float* __restrict__ bmha, float* __restrict__ out) {
    __shared__ float s_c[256];
    int b = blockIdx.x, ic = blockIdx.y;
    int tid = threadIdx.x;   // 512
    if (tid < 256) s_c[tid] = ctx[b * 2048 + ic * 256 + tid];
    __syncthreads();
    float acc = (ic == 0) ? bmha[tid] : 0.0f;
    const float* W = Wmha + (size_t)ic * 256 * 512;
    for (int i = 0; i < 256; i++) acc += s_c[i] * W[i * 512 + tid];
    atomicAdd(&out[b * 512 + tid], acc);
}

extern "C" void kernel_launch(void* const* d_in, const int* in_sizes, int n_in,
                              void* d_out, int out_size, void* d_ws, size_t ws_size,
                              hipStream_t stream) {
    const float* enc   = (const float*)d_in[0];
    const int*   xlens = (const int*)  d_in[1];
    const float* dec   = (const float*)d_in[2];
    const float* aw_st = (const float*)d_in[3];
    const float* Wenc  = (const float*)d_in[4];
    const float* benc  = (const float*)d_in[5];
    const float* Wdec  = (const float*)d_in[6];
    const float* Wconv = (const float*)d_in[7];
    const float* convw = (const float*)d_in[8];
    const float* v     = (const float*)d_in[9];
    const float* Wmha  = (const float*)d_in[10];
    const float* bmha  = (const float*)d_in[11];
    float* out = (float*)d_out;            // [8192 context_vec][96000 aw]

    char* ws = (char*)d_ws;
    float* energy          = (float*)(ws);                    // 384000 B
    float* ctx             = (float*)(ws + 384000);           // 131072 B
    float* decA            = (float*)(ws + 515072);           // 131072 B
    unsigned short* WencTp = (unsigned short*)(ws + 646144);  // 4*512*576*2 = 2359296 B
    unsigned short* convAB = (unsigned short*)(ws + 3005440); // 2*24000*64*2 = 6144000 B
    unsigned short* encB   = (unsigned short*)(ws + 9149440); // 24000*512*2 = 24576000 B
    float* aw = out + 8192;

    k_prep    <<<7536, 256, 0, stream>>>(enc, encB, Wenc, Wconv, WencTp,
                                         dec, Wdec, benc, decA, out,
                                         aw_st, convw, convAB, (float*)ws);
    k_energy  <<<dim3(188, 8), 256, 0, stream>>>(encB, WencTp, convAB, decA, v, energy);
    k_softmax <<<dim3(16, 4), 256, 0, stream>>>(energy, xlens, aw);
    k_ctx     <<<dim3(16, 12), 256, 0, stream>>>(encB, aw, ctx);
    k_proj    <<<dim3(16, 8), 512, 0, stream>>>(ctx, Wmha, bmha, out);
}

// Round 17
// 152.989 us; speedup vs baseline: 1.0133x; 1.0002x over previous
//
#include <hip/hip_runtime.h>
#include <hip/hip_bf16.h>

#define B_ 16
#define T_ 1500
#define E_ 512
#define A_ 512
#define H_ 4
#define C_ 10
#define K_ 201
#define M_ (B_*T_)   // 24000
#define KW_ 544      // 512 enc + 32 conv-channel K-rows

typedef __attribute__((ext_vector_type(8))) short short8v;    // 8 bf16
typedef __attribute__((ext_vector_type(4))) float f32x4;
typedef __attribute__((ext_vector_type(4))) unsigned short ushort4v;
typedef __attribute__((ext_vector_type(8))) unsigned short ushort8v;

typedef __attribute__((address_space(1))) const char gch;
typedef __attribute__((address_space(3))) char lch;

__device__ __forceinline__ void gload16(const void* g, void* l) {
    __builtin_amdgcn_global_load_lds((gch*)g, (lch*)l, 16, 0, 0);
}

__device__ inline unsigned short f2bf(float x) {
    unsigned int u = __float_as_uint(x);
    return (unsigned short)((u + 0x7fffu + ((u >> 16) & 1u)) >> 16);   // RNE
}

// ---- fused prep: enc->bf16 | W_enc transpose + W_conv pack | decA | conv ----
__global__ void k_prep(const float* __restrict__ enc, unsigned short* __restrict__ encB,
                       const float* __restrict__ Wenc, const float* __restrict__ Wconv,
                       unsigned short* __restrict__ WencTp,
                       const float* __restrict__ dec, const float* __restrict__ Wdec,
                       const float* __restrict__ benc, float* __restrict__ decA,
                       float* __restrict__ out,
                       const float* __restrict__ aw_step, const float* __restrict__ conv_w,
                       unsigned short* __restrict__ convA, float* __restrict__ wszero) {
    __shared__ float smemf[4456];
    int bid = blockIdx.x;
    int tid = threadIdx.x;

    if (bid < 6000) {                       // ---- enc [24000][512] f32 -> bf16
        int i = bid * 256 + tid;
        const float4* src = (const float4*)enc + (size_t)i * 2;
        float4 f0 = src[0], f1 = src[1];
        ushort8v o = { f2bf(f0.x), f2bf(f0.y), f2bf(f0.z), f2bf(f0.w),
                       f2bf(f1.x), f2bf(f1.y), f2bf(f1.z), f2bf(f1.w) };
        *(ushort8v*)&encB[(size_t)i * 8] = o;
        return;
    }
    if (bid < 7088) {                       // ---- W_enc transpose / W_conv pack
        int idx = bid - 6000;
        int bx = idx & 15, by = (idx >> 4) % 17, h = idx / 272;
        int tx = tid & 31, ty = tid >> 5;   // 32 x 8
        if (by == 16) {                     // conv-weight pack stripe
            int base = (h * 16 + bx) * 1024;
            #pragma unroll
            for (int k = 0; k < 4; k++) {
                int i2 = base + k * 256 + tid;
                int c = i2 & 31, n = (i2 >> 5) & 511, hh = i2 >> 14;
                float val = (c < C_) ? Wconv[(hh * C_ + c) * A_ + n] : 0.0f;
                WencTp[((size_t)(hh * A_ + n)) * KW_ + 512 + c] = f2bf(val);
            }
            return;
        }
        float (*tile)[33] = (float(*)[33])smemf;
        int e0 = bx * 32, a0 = by * 32;
        const float* src = Wenc + h * E_ * A_;
        #pragma unroll
        for (int i = 0; i < 4; i++) tile[ty + i*8][tx] = src[(e0 + ty + i*8) * A_ + a0 + tx];
        __syncthreads();
        unsigned short* dst = WencTp + (size_t)h * A_ * KW_;
        #pragma unroll
        for (int i = 0; i < 4; i++) dst[(size_t)(a0 + ty + i*8) * KW_ + e0 + tx] = f2bf(tile[tx][ty + i*8]);
        return;
    }
    if (bid < 7152) {                       // ---- decA + zero context_vec out
        int bh = bid - 7088, b = bh >> 2, h = bh & 3;
        int a = tid;
        if (bh < 32) out[bh * 256 + a] = 0.0f;
        float acc0 = 0.f, acc1 = 0.f;
        const float* W = Wdec + h * E_ * A_;
        const float* x = dec + b * 512;
        for (int d = 0; d < 512; d++) {
            float s = x[d];
            acc0 += s * W[d * A_ + a];
            acc1 += s * W[d * A_ + a + 256];
        }
        decA[bh * A_ + a]       = acc0 + benc[h * A_ + a];
        decA[bh * A_ + a + 256] = acc1 + benc[h * A_ + a + 256];
        return;
    }
    {                                       // ---- grouped conv + zero energy/ctx
        int i = bid - 7152;
        int b = i & 15, h = (i >> 4) & 3, tc = i >> 6;
        int t0 = tc * 250;
        float* seg = smemf;
        unsigned short* outl = (unsigned short*)(smemf + 456);
        {   // zero energy (96000 f32) + ctx (32768 f32)
            int idx = (i * 256 + tid) * 2;
            if (idx < 128768)     wszero[idx] = 0.0f;
            if (idx + 1 < 128768) wszero[idx + 1] = 0.0f;
        }
        for (int idx = tid; idx < 450; idx += 256) {
            int tt = t0 - 100 + idx;
            seg[idx] = (tt >= 0 && tt < T_) ? aw_step[(b * T_ + tt) * H_ + h] : 0.0f;
        }
        for (int idx = tid; idx < 8000; idx += 256) outl[idx] = 0;
        __syncthreads();
        if (tid < 250) {
            float acc[10] = {0,0,0,0,0,0,0,0,0,0};
            const float* cw = conv_w + h * C_ * K_;
            for (int k = 0; k < K_; k++) {
                float sv = seg[tid + k];
                #pragma unroll
                for (int c = 0; c < 10; c++) acc[c] += sv * cw[c * K_ + k];
            }
            #pragma unroll
            for (int c = 0; c < 10; c++) outl[tid * 32 + c] = f2bf(acc[c]);
        }
        __syncthreads();
        unsigned short* dst = convA + ((size_t)h * M_ + (size_t)b * T_ + t0) * 32;
        for (int idx = tid; idx < 2000; idx += 256)
            *(ushort4v*)&dst[idx * 4] = *(const ushort4v*)&outl[idx * 4];
    }
}

// ---- fused energy GEMM: 128x128, BK=32, 17 uniform K-steps, TRIPLE-buffered
// (48KB LDS -> 3 blocks/CU) with 2-deep prefetch (VERIFIED R12 schedule):
// step s stages step s+2; vmcnt(8) steady / (4)/(0) tail; two barriers/step.
// Swizzle both-sides (rule #21, verified conflict-free). Swapped MFMA
// operands (C^T) -> 2-shfl epilogue (verified R12).
__launch_bounds__(256, 3)
__global__ void k_energy(const unsigned short* __restrict__ encB,
                         const unsigned short* __restrict__ WencTp,
                         const unsigned short* __restrict__ convA,
                         const float* __restrict__ decA,
                         const float* __restrict__ v,
                         float* __restrict__ energy) {
    __shared__ unsigned short As[3][4096];   // [buf][128 rows x 32 k]
    __shared__ unsigned short Bs[3][4096];
    int m0 = blockIdx.x * 128;                // 188 M-tiles (last clamps rows)
    int h  = blockIdx.y >> 2;
    int n0 = (blockIdx.y & 3) * 128;
    int tid = threadIdx.x;
    int lane = tid & 63, w = tid >> 6;
    int wr = w >> 1, wc = w & 1;
    int lc = lane & 15, lr16 = lane >> 4;

    // staging: 8 chunks x 16 rows; row = chunk*16 + (lane>>2), 16B slot lane&3;
    // pre-swizzled source slot = slot ^ ((row>>1)&3)  [verified: conflicts = 0]
    int srow  = lane >> 2;
    int sslot = (lane & 3) ^ ((lane >> 3) & 3);

    const char* pa[2]; const char* pb[2]; const char* pca[2];
    #pragma unroll
    for (int i = 0; i < 2; i++) {
        int c = i * 4 + w;                  // chunk 0..7
        int row = c * 16 + srow;
        int grow = min(m0 + row, M_ - 1);
        pa[i]  = (const char*)encB + ((size_t)grow * 512 + sslot * 8) * 2;
        pb[i]  = (const char*)WencTp + ((size_t)(h * 512 + n0 + row) * KW_ + sslot * 8) * 2;
        pca[i] = (const char*)convA + (((size_t)h * M_ + grow) * 32 + sslot * 8) * 2;
    }

    // ds_read swizzled k-slot (elems); row parity comes from lc
    int kslot = (lr16 ^ ((lc >> 1) & 3)) * 8;

    f32x4 acc[4][4] = {};

    // prologue: stage steps 0 and 1 into bufs 0 and 1 (8 loads in flight)
    #pragma unroll
    for (int i = 0; i < 2; i++) {
        int c = i * 4 + w;
        gload16(pa[i],      (char*)As[0] + c * 1024);
        gload16(pb[i],      (char*)Bs[0] + c * 1024);
        gload16(pa[i] + 64, (char*)As[1] + c * 1024);
        gload16(pb[i] + 64, (char*)Bs[1] + c * 1024);
    }

    int bc = 0, bn1 = 1, bn2 = 2;            // compute buf, +1, +2 (rotating)
    for (int s = 0; s < 17; ++s) {
        int t = s + 2;                        // prefetch target step
        if (t <= 16) {
            #pragma unroll
            for (int i = 0; i < 2; i++) {
                int c = i * 4 + w;
                const char* asrc = (t < 16) ? pa[i] + t * 64 : pca[i];
                const char* bsrc = (t < 16) ? pb[i] + t * 64 : pb[i] + 16 * 64;
                gload16(asrc, (char*)As[bn2] + c * 1024);
                gload16(bsrc, (char*)Bs[bn2] + c * 1024);
            }
        }
        if (s <= 14)      asm volatile("s_waitcnt vmcnt(8)" ::: "memory");
        else if (s == 15) asm volatile("s_waitcnt vmcnt(4)" ::: "memory");
        else              asm volatile("s_waitcnt vmcnt(0)" ::: "memory");
        __builtin_amdgcn_s_barrier();         // batch_s landed block-wide
        __builtin_amdgcn_sched_barrier(0);    // no ds_read hoist above barrier
        {
            short8v a[4], b[4];
            #pragma unroll
            for (int mi = 0; mi < 4; mi++)
                a[mi] = *(const short8v*)&As[bc][(wr * 64 + mi * 16 + lc) * 32 + kslot];
            #pragma unroll
            for (int ni = 0; ni < 4; ni++)
                b[ni] = *(const short8v*)&Bs[bc][(wc * 64 + ni * 16 + lc) * 32 + kslot];
            // swapped operands -> acc holds C^T: lane col = m (lc), rows = n
            #pragma unroll
            for (int mi = 0; mi < 4; mi++)
                #pragma unroll
                for (int ni = 0; ni < 4; ni++)
                    acc[mi][ni] = __builtin_amdgcn_mfma_f32_16x16x32_bf16(b[ni], a[mi], acc[mi][ni], 0, 0, 0);
        }
        __builtin_amdgcn_sched_barrier(0);    // no ds_read sink below barrier
        __builtin_amdgcn_s_barrier();         // done reading bc; may overwrite
        int tmp = bc; bc = bn1; bn1 = bn2; bn2 = tmp;
    }

    // epilogue: C^T layout -> m = wr*64+mi*16+lc ; n = wc*64+ni*16+lr16*4+r.
    #pragma unroll
    for (int mi = 0; mi < 4; mi++) {
        int mrow = m0 + wr * 64 + mi * 16 + lc;
        if (mrow < M_) {
            int bb = mrow / 1500;
            const float* dA = decA + (bb * 4 + h) * 512;
            float s = 0.f;
            #pragma unroll
            for (int ni = 0; ni < 4; ni++) {
                #pragma unroll
                for (int r = 0; r < 4; r++) {
                    int n = n0 + wc * 64 + ni * 16 + lr16 * 4 + r;
                    float xv = acc[mi][ni][r] + dA[n];
                    // tanh(x) = 1 - 2/(e^2x + 1); saturates correctly at +-inf
                    float tt = __builtin_amdgcn_rcpf(__expf(2.0f * xv) + 1.0f);
                    float vv = v[h * 512 + n];
                    s += __builtin_fmaf(-2.0f * tt, vv, vv);
                }
            }
            s += __shfl_xor(s, 16);
            s += __shfl_xor(s, 32);
            if (lr16 == 0) atomicAdd(&energy[(size_t)mrow * 4 + h], s);
        }
    }
}

// ---- masked softmax over T ----
__global__ void k_softmax(const float* __restrict__ energy, const int* __restrict__ xlens,
                          float* __restrict__ aw) {
    __shared__ float red[8];
    int b = blockIdx.x, h = blockIdx.y;
    int tid = threadIdx.x;
    int len = xlens[b];
    float e[6];
    float m = -1e30f;
    #pragma unroll
    for (int i = 0; i < 6; i++) {
        int t = tid + i * 256;
        float val = 0.0f;
        if (t < T_) {
            val = (t < len) ? energy[(size_t)(b * T_ + t) * H_ + h] : 0.0f;
            m = fmaxf(m, val);
        }
        e[i] = val;
    }
    #pragma unroll
    for (int mk = 1; mk < 64; mk <<= 1) m = fmaxf(m, __shfl_xor(m, mk));
    if ((tid & 63) == 0) red[tid >> 6] = m;
    __syncthreads();
    m = fmaxf(fmaxf(red[0], red[1]), fmaxf(red[2], red[3]));
    float ssum = 0.f;
    #pragma unroll
    for (int i = 0; i < 6; i++) {
        int t = tid + i * 256;
        if (t < T_) { e[i] = expf(e[i] - m); ssum += e[i]; }
    }
    #pragma unroll
    for (int mk = 1; mk < 64; mk <<= 1) ssum += __shfl_xor(ssum, mk);
    if ((tid & 63) == 0) red[4 + (tid >> 6)] = ssum;
    __syncthreads();
    float inv = 1.0f / (red[4] + red[5] + red[6] + red[7]);
    #pragma unroll
    for (int i = 0; i < 6; i++) {
        int t = tid + i * 256;
        if (t < T_) aw[(size_t)(b * T_ + t) * H_ + h] = e[i] * inv;
    }
}

// ---- ctx[b][h][e] = sum_t aw[b,t,h] * encB[b,t,e]  (bf16 enc read) ----
__global__ void k_ctx(const unsigned short* __restrict__ encB, const float* __restrict__ aw,
                      float* __restrict__ ctx) {
    __shared__ float s_aw[500];
    int b = blockIdx.x, tc = blockIdx.y;   // grid (16, 12)
    int t0 = tc * 125;
    int tid = threadIdx.x;
    for (int idx = tid; idx < 500; idx += 256)
        s_aw[idx] = aw[(size_t)b * T_ * H_ + t0 * H_ + idx];
    __syncthreads();
    int e = tid * 2;
    float a00=0,a01=0,a10=0,a11=0,a20=0,a21=0,a30=0,a31=0;
    for (int tl = 0; tl < 125; tl++) {
        unsigned int u = *(const unsigned int*)&encB[(size_t)(b * T_ + t0 + tl) * E_ + e];
        float e0 = __uint_as_float((u & 0xffffu) << 16);
        float e1 = __uint_as_float(u & 0xffff0000u);
        float w0 = s_aw[tl*4+0], w1 = s_aw[tl*4+1], w2 = s_aw[tl*4+2], w3 = s_aw[tl*4+3];
        a00 += e0*w0; a01 += e1*w0; a10 += e0*w1; a11 += e1*w1;
        a20 += e0*w2; a21 += e1*w2; a30 += e0*w3; a31 += e1*w3;
    }
    atomicAdd(&ctx[b*2048 + 0*512 + e],   a00); atomicAdd(&ctx[b*2048 + 0*512 + e+1], a01);
    atomicAdd(&ctx[b*2048 + 1*512 + e],   a10); atomicAdd(&ctx[b*2048 + 1*512 + e+1], a11);
    atomicAdd(&ctx[b*2048 + 2*512 + e],   a20); atomicAdd(&ctx[b*2048 + 2*512 + e+1], a21);
    atomicAdd(&ctx[b*2048 + 3*512 + e],   a30); atomicAdd(&ctx[b*2048 + 3*512 + e+1], a31);
}

// ---- context_vec: W_mha read ONCE total. Block bid covers 32 K-rows of 2048;
// accumulates all 16 batches against the same W column slice. ----
__global__ void k_proj(const float* __restrict__ ctx, const float* __restrict__ Wmha,
                       const float* __restrict__ bmha, float* __restrict__ out) {
    __shared__ float s_c[16][32];
    int r0 = blockIdx.x * 32;     // 64 blocks
    int tid = threadIdx.x;        // 512 = output col j
    {
        int b = tid >> 5, i = tid & 31;
        s_c[b][i] = ctx[b * 2048 + r0 + i];
    }
    __syncthreads();
    float acc[16] = {};
    for (int i = 0; i < 32; i++) {
        float wv = Wmha[(size_t)(r0 + i) * 512 + tid];
        #pragma unroll
        for (int b = 0; b < 16; b++) acc[b] += s_c[b][i] * wv;
    }
    if (blockIdx.x == 0) {
        float bias = bmha[tid];
        #pragma unroll
        for (int b = 0; b < 16; b++) acc[b] += bias;
    }
    #pragma unroll
    for (int b = 0; b < 16; b++) atomicAdd(&out[b * 512 + tid], acc[b]);
}

extern "C" void kernel_launch(void* const* d_in, const int* in_sizes, int n_in,
                              void* d_out, int out_size, void* d_ws, size_t ws_size,
                              hipStream_t stream) {
    const float* enc   = (const float*)d_in[0];
    const int*   xlens = (const int*)  d_in[1];
    const float* dec   = (const float*)d_in[2];
    const float* aw_st = (const float*)d_in[3];
    const float* Wenc  = (const float*)d_in[4];
    const float* benc  = (const float*)d_in[5];
    const float* Wdec  = (const float*)d_in[6];
    const float* Wconv = (const float*)d_in[7];
    const float* convw = (const float*)d_in[8];
    const float* v     = (const float*)d_in[9];
    const float* Wmha  = (const float*)d_in[10];
    const float* bmha  = (const float*)d_in[11];
    float* out = (float*)d_out;            // [8192 context_vec][96000 aw]

    char* ws = (char*)d_ws;
    float* energy          = (float*)(ws);                    // 384000 B
    float* ctx             = (float*)(ws + 384000);           // 131072 B
    float* decA            = (float*)(ws + 515072);           // 131072 B
    unsigned short* WencTp = (unsigned short*)(ws + 646144);  // 4*512*544*2 = 2228224 B
    unsigned short* convA  = (unsigned short*)(ws + 2874368); // 4*24000*32*2 = 6144000 B
    unsigned short* encB   = (unsigned short*)(ws + 9018368); // 24000*512*2 = 24576000 B
    float* aw = out + 8192;

    k_prep    <<<7536, 256, 0, stream>>>(enc, encB, Wenc, Wconv, WencTp,
                                         dec, Wdec, benc, decA, out,
                                         aw_st, convw, convA, (float*)ws);
    k_energy  <<<dim3(188, 16), 256, 0, stream>>>(encB, WencTp, convA, decA, v, energy);
    k_softmax <<<dim3(16, 4), 256, 0, stream>>>(energy, xlens, aw);
    k_ctx     <<<dim3(16, 12), 256, 0, stream>>>(encB, aw, ctx);
    k_proj    <<<64, 512, 0, stream>>>(ctx, Wmha, bmha, out);
}

// Round 20
// 151.744 us; speedup vs baseline: 1.0216x; 1.0082x over previous
//
#include <hip/hip_runtime.h>
#include <hip/hip_bf16.h>

#define B_ 16
#define T_ 1500
#define E_ 512
#define A_ 512
#define H_ 4
#define C_ 10
#define K_ 201
#define M_ (B_*T_)   // 24000
#define KW_ 544      // 512 enc + 32 conv-channel K-rows

typedef __attribute__((ext_vector_type(8))) short short8v;    // 8 bf16
typedef __attribute__((ext_vector_type(4))) float f32x4;
typedef __attribute__((ext_vector_type(4))) unsigned short ushort4v;
typedef __attribute__((ext_vector_type(8))) unsigned short ushort8v;

typedef __attribute__((address_space(1))) const char gch;
typedef __attribute__((address_space(3))) char lch;

__device__ __forceinline__ void gload16(const void* g, void* l) {
    __builtin_amdgcn_global_load_lds((gch*)g, (lch*)l, 16, 0, 0);
}

__device__ inline unsigned short f2bf(float x) {
    unsigned int u = __float_as_uint(x);
    return (unsigned short)((u + 0x7fffu + ((u >> 16) & 1u)) >> 16);   // RNE
}

// ---- fused prep: enc->bf16 | W_enc transpose + W_conv pack | decA | conv ----
__global__ void k_prep(const float* __restrict__ enc, unsigned short* __restrict__ encB,
                       const float* __restrict__ Wenc, const float* __restrict__ Wconv,
                       unsigned short* __restrict__ WencTp,
                       const float* __restrict__ dec, const float* __restrict__ Wdec,
                       const float* __restrict__ benc, float* __restrict__ decA,
                       float* __restrict__ out,
                       const float* __restrict__ aw_step, const float* __restrict__ conv_w,
                       unsigned short* __restrict__ convA, float* __restrict__ wszero) {
    __shared__ float smemf[4456];
    int bid = blockIdx.x;
    int tid = threadIdx.x;

    if (bid < 6000) {                       // ---- enc [24000][512] f32 -> bf16
        int i = bid * 256 + tid;
        const float4* src = (const float4*)enc + (size_t)i * 2;
        float4 f0 = src[0], f1 = src[1];
        ushort8v o = { f2bf(f0.x), f2bf(f0.y), f2bf(f0.z), f2bf(f0.w),
                       f2bf(f1.x), f2bf(f1.y), f2bf(f1.z), f2bf(f1.w) };
        *(ushort8v*)&encB[(size_t)i * 8] = o;
        return;
    }
    if (bid < 7088) {                       // ---- W_enc transpose / W_conv pack
        int idx = bid - 6000;
        int bx = idx & 15, by = (idx >> 4) % 17, h = idx / 272;
        int tx = tid & 31, ty = tid >> 5;   // 32 x 8
        if (by == 16) {                     // conv-weight pack stripe
            int base = (h * 16 + bx) * 1024;
            #pragma unroll
            for (int k = 0; k < 4; k++) {
                int i2 = base + k * 256 + tid;
                int c = i2 & 31, n = (i2 >> 5) & 511, hh = i2 >> 14;
                float val = (c < C_) ? Wconv[(hh * C_ + c) * A_ + n] : 0.0f;
                WencTp[((size_t)(hh * A_ + n)) * KW_ + 512 + c] = f2bf(val);
            }
            return;
        }
        float (*tile)[33] = (float(*)[33])smemf;
        int e0 = bx * 32, a0 = by * 32;
        const float* src = Wenc + h * E_ * A_;
        #pragma unroll
        for (int i = 0; i < 4; i++) tile[ty + i*8][tx] = src[(e0 + ty + i*8) * A_ + a0 + tx];
        __syncthreads();
        unsigned short* dst = WencTp + (size_t)h * A_ * KW_;
        #pragma unroll
        for (int i = 0; i < 4; i++) dst[(size_t)(a0 + ty + i*8) * KW_ + e0 + tx] = f2bf(tile[tx][ty + i*8]);
        return;
    }
    if (bid < 7152) {                       // ---- decA + zero context_vec out
        int bh = bid - 7088, b = bh >> 2, h = bh & 3;
        int a = tid;
        if (bh < 32) out[bh * 256 + a] = 0.0f;
        float acc0 = 0.f, acc1 = 0.f;
        const float* W = Wdec + h * E_ * A_;
        const float* x = dec + b * 512;
        for (int d = 0; d < 512; d++) {
            float s = x[d];
            acc0 += s * W[d * A_ + a];
            acc1 += s * W[d * A_ + a + 256];
        }
        decA[bh * A_ + a]       = acc0 + benc[h * A_ + a];
        decA[bh * A_ + a + 256] = acc1 + benc[h * A_ + a + 256];
        return;
    }
    {                                       // ---- grouped conv + zero energy/ctx
        int i = bid - 7152;
        int b = i & 15, h = (i >> 4) & 3, tc = i >> 6;
        int t0 = tc * 250;
        float* seg = smemf;
        unsigned short* outl = (unsigned short*)(smemf + 456);
        {   // zero energy (96000 f32) + ctx (32768 f32)
            int idx = (i * 256 + tid) * 2;
            if (idx < 128768)     wszero[idx] = 0.0f;
            if (idx + 1 < 128768) wszero[idx + 1] = 0.0f;
        }
        for (int idx = tid; idx < 450; idx += 256) {
            int tt = t0 - 100 + idx;
            seg[idx] = (tt >= 0 && tt < T_) ? aw_step[(b * T_ + tt) * H_ + h] : 0.0f;
        }
        for (int idx = tid; idx < 8000; idx += 256) outl[idx] = 0;
        __syncthreads();
        if (tid < 250) {
            float acc[10] = {0,0,0,0,0,0,0,0,0,0};
            const float* cw = conv_w + h * C_ * K_;
            for (int k = 0; k < K_; k++) {
                float sv = seg[tid + k];
                #pragma unroll
                for (int c = 0; c < 10; c++) acc[c] += sv * cw[c * K_ + k];
            }
            #pragma unroll
            for (int c = 0; c < 10; c++) outl[tid * 32 + c] = f2bf(acc[c]);
        }
        __syncthreads();
        unsigned short* dst = convA + ((size_t)h * M_ + (size_t)b * T_ + t0) * 32;
        for (int idx = tid; idx < 2000; idx += 256)
            *(ushort4v*)&dst[idx * 4] = *(const ushort4v*)&outl[idx * 4];
    }
}

// ---- fused energy GEMM: 128x128, BK=32, 17 uniform K-steps, TRIPLE-buffered
// (48KB LDS -> 3 blocks/CU) with 2-deep prefetch (VERIFIED R12 schedule):
// step s stages step s+2; vmcnt(8) steady / (4)/(0) tail; two barriers/step.
// Swizzle both-sides (rule #21, verified conflict-free). Swapped MFMA
// operands (C^T) -> 2-shfl epilogue (verified R12).
// T5 probe: setprio around MFMA cluster (3 staggered blocks/CU = phase
// diversity -> scheduler can favor MFMA-phase waves).
__launch_bounds__(256, 3)
__global__ void k_energy(const unsigned short* __restrict__ encB,
                         const unsigned short* __restrict__ WencTp,
                         const unsigned short* __restrict__ convA,
                         const float* __restrict__ decA,
                         const float* __restrict__ v,
                         float* __restrict__ energy) {
    __shared__ unsigned short As[3][4096];   // [buf][128 rows x 32 k]
    __shared__ unsigned short Bs[3][4096];
    int m0 = blockIdx.x * 128;                // 188 M-tiles (last clamps rows)
    int h  = blockIdx.y >> 2;
    int n0 = (blockIdx.y & 3) * 128;
    int tid = threadIdx.x;
    int lane = tid & 63, w = tid >> 6;
    int wr = w >> 1, wc = w & 1;
    int lc = lane & 15, lr16 = lane >> 4;

    // staging: 8 chunks x 16 rows; row = chunk*16 + (lane>>2), 16B slot lane&3;
    // pre-swizzled source slot = slot ^ ((row>>1)&3)  [verified: conflicts = 0]
    int srow  = lane >> 2;
    int sslot = (lane & 3) ^ ((lane >> 3) & 3);

    const char* pa[2]; const char* pb[2]; const char* pca[2];
    #pragma unroll
    for (int i = 0; i < 2; i++) {
        int c = i * 4 + w;                  // chunk 0..7
        int row = c * 16 + srow;
        int grow = min(m0 + row, M_ - 1);
        pa[i]  = (const char*)encB + ((size_t)grow * 512 + sslot * 8) * 2;
        pb[i]  = (const char*)WencTp + ((size_t)(h * 512 + n0 + row) * KW_ + sslot * 8) * 2;
        pca[i] = (const char*)convA + (((size_t)h * M_ + grow) * 32 + sslot * 8) * 2;
    }

    // ds_read swizzled k-slot (elems); row parity comes from lc
    int kslot = (lr16 ^ ((lc >> 1) & 3)) * 8;

    f32x4 acc[4][4] = {};

    // prologue: stage steps 0 and 1 into bufs 0 and 1 (8 loads in flight)
    #pragma unroll
    for (int i = 0; i < 2; i++) {
        int c = i * 4 + w;
        gload16(pa[i],      (char*)As[0] + c * 1024);
        gload16(pb[i],      (char*)Bs[0] + c * 1024);
        gload16(pa[i] + 64, (char*)As[1] + c * 1024);
        gload16(pb[i] + 64, (char*)Bs[1] + c * 1024);
    }

    int bc = 0, bn1 = 1, bn2 = 2;            // compute buf, +1, +2 (rotating)
    for (int s = 0; s < 17; ++s) {
        int t = s + 2;                        // prefetch target step
        if (t <= 16) {
            #pragma unroll
            for (int i = 0; i < 2; i++) {
                int c = i * 4 + w;
                const char* asrc = (t < 16) ? pa[i] + t * 64 : pca[i];
                const char* bsrc = (t < 16) ? pb[i] + t * 64 : pb[i] + 16 * 64;
                gload16(asrc, (char*)As[bn2] + c * 1024);
                gload16(bsrc, (char*)Bs[bn2] + c * 1024);
            }
        }
        if (s <= 14)      asm volatile("s_waitcnt vmcnt(8)" ::: "memory");
        else if (s == 15) asm volatile("s_waitcnt vmcnt(4)" ::: "memory");
        else              asm volatile("s_waitcnt vmcnt(0)" ::: "memory");
        __builtin_amdgcn_s_barrier();         // batch_s landed block-wide
        __builtin_amdgcn_sched_barrier(0);    // no ds_read hoist above barrier
        {
            short8v a[4], b[4];
            #pragma unroll
            for (int mi = 0; mi < 4; mi++)
                a[mi] = *(const short8v*)&As[bc][(wr * 64 + mi * 16 + lc) * 32 + kslot];
            #pragma unroll
            for (int ni = 0; ni < 4; ni++)
                b[ni] = *(const short8v*)&Bs[bc][(wc * 64 + ni * 16 + lc) * 32 + kslot];
            // swapped operands -> acc holds C^T: lane col = m (lc), rows = n
            __builtin_amdgcn_s_setprio(1);
            #pragma unroll
            for (int mi = 0; mi < 4; mi++)
                #pragma unroll
                for (int ni = 0; ni < 4; ni++)
                    acc[mi][ni] = __builtin_amdgcn_mfma_f32_16x16x32_bf16(b[ni], a[mi], acc[mi][ni], 0, 0, 0);
            __builtin_amdgcn_s_setprio(0);
        }
        __builtin_amdgcn_sched_barrier(0);    // no ds_read sink below barrier
        __builtin_amdgcn_s_barrier();         // done reading bc; may overwrite
        int tmp = bc; bc = bn1; bn1 = bn2; bn2 = tmp;
    }

    // epilogue: C^T layout -> m = wr*64+mi*16+lc ; n = wc*64+ni*16+lr16*4+r.
    #pragma unroll
    for (int mi = 0; mi < 4; mi++) {
        int mrow = m0 + wr * 64 + mi * 16 + lc;
        if (mrow < M_) {
            int bb = mrow / 1500;
            const float* dA = decA + (bb * 4 + h) * 512;
            float s = 0.f;
            #pragma unroll
            for (int ni = 0; ni < 4; ni++) {
                #pragma unroll
                for (int r = 0; r < 4; r++) {
                    int n = n0 + wc * 64 + ni * 16 + lr16 * 4 + r;
                    float xv = acc[mi][ni][r] + dA[n];
                    // tanh(x) = 1 - 2/(e^2x + 1); saturates correctly at +-inf
                    float tt = __builtin_amdgcn_rcpf(__expf(2.0f * xv) + 1.0f);
                    float vv = v[h * 512 + n];
                    s += __builtin_fmaf(-2.0f * tt, vv, vv);
                }
            }
            s += __shfl_xor(s, 16);
            s += __shfl_xor(s, 32);
            if (lr16 == 0) atomicAdd(&energy[(size_t)mrow * 4 + h], s);
        }
    }
}

// ---- masked softmax over T ----
__global__ void k_softmax(const float* __restrict__ energy, const int* __restrict__ xlens,
                          float* __restrict__ aw) {
    __shared__ float red[8];
    int b = blockIdx.x, h = blockIdx.y;
    int tid = threadIdx.x;
    int len = xlens[b];
    float e[6];
    float m = -1e30f;
    #pragma unroll
    for (int i = 0; i < 6; i++) {
        int t = tid + i * 256;
        float val = 0.0f;
        if (t < T_) {
            val = (t < len) ? energy[(size_t)(b * T_ + t) * H_ + h] : 0.0f;
            m = fmaxf(m, val);
        }
        e[i] = val;
    }
    #pragma unroll
    for (int mk = 1; mk < 64; mk <<= 1) m = fmaxf(m, __shfl_xor(m, mk));
    if ((tid & 63) == 0) red[tid >> 6] = m;
    __syncthreads();
    m = fmaxf(fmaxf(red[0], red[1]), fmaxf(red[2], red[3]));
    float ssum = 0.f;
    #pragma unroll
    for (int i = 0; i < 6; i++) {
        int t = tid + i * 256;
        if (t < T_) { e[i] = expf(e[i] - m); ssum += e[i]; }
    }
    #pragma unroll
    for (int mk = 1; mk < 64; mk <<= 1) ssum += __shfl_xor(ssum, mk);
    if ((tid & 63) == 0) red[4 + (tid >> 6)] = ssum;
    __syncthreads();
    float inv = 1.0f / (red[4] + red[5] + red[6] + red[7]);
    #pragma unroll
    for (int i = 0; i < 6; i++) {
        int t = tid + i * 256;
        if (t < T_) aw[(size_t)(b * T_ + t) * H_ + h] = e[i] * inv;
    }
}

// ---- ctx[b][h][e] = sum_t aw[b,t,h] * encB[b,t,e]  (bf16 enc read) ----
__global__ void k_ctx(const unsigned short* __restrict__ encB, const float* __restrict__ aw,
                      float* __restrict__ ctx) {
    __shared__ float s_aw[500];
    int b = blockIdx.x, tc = blockIdx.y;   // grid (16, 12)
    int t0 = tc * 125;
    int tid = threadIdx.x;
    for (int idx = tid; idx < 500; idx += 256)
        s_aw[idx] = aw[(size_t)b * T_ * H_ + t0 * H_ + idx];
    __syncthreads();
    int e = tid * 2;
    float a00=0,a01=0,a10=0,a11=0,a20=0,a21=0,a30=0,a31=0;
    for (int tl = 0; tl < 125; tl++) {
        unsigned int u = *(const unsigned int*)&encB[(size_t)(b * T_ + t0 + tl) * E_ + e];
        float e0 = __uint_as_float((u & 0xffffu) << 16);
        float e1 = __uint_as_float(u & 0xffff0000u);
        float w0 = s_aw[tl*4+0], w1 = s_aw[tl*4+1], w2 = s_aw[tl*4+2], w3 = s_aw[tl*4+3];
        a00 += e0*w0; a01 += e1*w0; a10 += e0*w1; a11 += e1*w1;
        a20 += e0*w2; a21 += e1*w2; a30 += e0*w3; a31 += e1*w3;
    }
    atomicAdd(&ctx[b*2048 + 0*512 + e],   a00); atomicAdd(&ctx[b*2048 + 0*512 + e+1], a01);
    atomicAdd(&ctx[b*2048 + 1*512 + e],   a10); atomicAdd(&ctx[b*2048 + 1*512 + e+1], a11);
    atomicAdd(&ctx[b*2048 + 2*512 + e],   a20); atomicAdd(&ctx[b*2048 + 2*512 + e+1], a21);
    atomicAdd(&ctx[b*2048 + 3*512 + e],   a30); atomicAdd(&ctx[b*2048 + 3*512 + e+1], a31);
}

// ---- context_vec: W_mha read ONCE total. Block bid covers 32 K-rows of 2048;
// accumulates all 16 batches against the same W column slice. ----
__global__ void k_proj(const float* __restrict__ ctx, const float* __restrict__ Wmha,
                       const float* __restrict__ bmha, float* __restrict__ out) {
    __shared__ float s_c[16][32];
    int r0 = blockIdx.x * 32;     // 64 blocks
    int tid = threadIdx.x;        // 512 = output col j
    {
        int b = tid >> 5, i = tid & 31;
        s_c[b][i] = ctx[b * 2048 + r0 + i];
    }
    __syncthreads();
    float acc[16] = {};
    for (int i = 0; i < 32; i++) {
        float wv = Wmha[(size_t)(r0 + i) * 512 + tid];
        #pragma unroll
        for (int b = 0; b < 16; b++) acc[b] += s_c[b][i] * wv;
    }
    if (blockIdx.x == 0) {
        float bias = bmha[tid];
        #pragma unroll
        for (int b = 0; b < 16; b++) acc[b] += bias;
    }
    #pragma unroll
    for (int b = 0; b < 16; b++) atomicAdd(&out[b * 512 + tid], acc[b]);
}

extern "C" void kernel_launch(void* const* d_in, const int* in_sizes, int n_in,
                              void* d_out, int out_size, void* d_ws, size_t ws_size,
                              hipStream_t stream) {
    const float* enc   = (const float*)d_in[0];
    const int*   xlens = (const int*)  d_in[1];
    const float* dec   = (const float*)d_in[2];
    const float* aw_st = (const float*)d_in[3];
    const float* Wenc  = (const float*)d_in[4];
    const float* benc  = (const float*)d_in[5];
    const float* Wdec  = (const float*)d_in[6];
    const float* Wconv = (const float*)d_in[7];
    const float* convw = (const float*)d_in[8];
    const float* v     = (const float*)d_in[9];
    const float* Wmha  = (const float*)d_in[10];
    const float* bmha  = (const float*)d_in[11];
    float* out = (float*)d_out;            // [8192 context_vec][96000 aw]

    char* ws = (char*)d_ws;
    float* energy          = (float*)(ws);                    // 384000 B
    float* ctx             = (float*)(ws + 384000);           // 131072 B
    float* decA            = (float*)(ws + 515072);           // 131072 B
    unsigned short* WencTp = (unsigned short*)(ws + 646144);  // 4*512*544*2 = 2228224 B
    unsigned short* convA  = (unsigned short*)(ws + 2874368); // 4*24000*32*2 = 6144000 B
    unsigned short* encB   = (unsigned short*)(ws + 9018368); // 24000*512*2 = 24576000 B
    float* aw = out + 8192;

    k_prep    <<<7536, 256, 0, stream>>>(enc, encB, Wenc, Wconv, WencTp,
                                         dec, Wdec, benc, decA, out,
                                         aw_st, convw, convA, (float*)ws);
    k_energy  <<<dim3(188, 16), 256, 0, stream>>>(encB, WencTp, convA, decA, v, energy);
    k_softmax <<<dim3(16, 4), 256, 0, stream>>>(energy, xlens, aw);
    k_ctx     <<<dim3(16, 12), 256, 0, stream>>>(encB, aw, ctx);
    k_proj    <<<64, 512, 0, stream>>>(ctx, Wmha, bmha, out);
}